// Round 1
// 148.313 us; speedup vs baseline: 1.0276x; 1.0276x over previous
//
#include <hip/hip_runtime.h>
#include <stdint.h>

#define N_BASES 5
#define WELEM (128 * 128 * 3 * 3) /* 147456 per base */

typedef __attribute__((ext_vector_type(4))) float f32x4;
typedef __attribute__((ext_vector_type(8))) short bf16x8;

__device__ __forceinline__ unsigned short f2bf(float v) {
  union { float f; uint32_t u; } un;
  un.f = v;
  uint32_t r = un.u + 0x7FFFu + ((un.u >> 16) & 1u);
  return (unsigned short)(r >> 16);
}

__device__ __forceinline__ void glds16(const void* g, void* l) {
  __builtin_amdgcn_global_load_lds(
      (const __attribute__((address_space(1))) void*)g,
      (__attribute__((address_space(3))) void*)l, 16, 0, 0);
}

// ---- kernel 1 (fused): blocks 0..1855 = x NCHW fp32 -> padded NHWC bf16;
//      blocks 1856..2175 = per-(base,chunk) |w| partial sums.
__global__ __launch_bounds__(256) void prep_fused(
    const float* __restrict__ x, const float* __restrict__ w,
    unsigned short* __restrict__ xp, float* __restrict__ csum_part) {
  int bi = blockIdx.x;
  if (bi >= 1856) {
    int id = bi - 1856;
    int n = id >> 6;
    int chunk = id & 63;
    const f32x4* wb = (const f32x4*)(w + (size_t)n * WELEM + chunk * 2304);
    float s = 0.f;
    for (int i = threadIdx.x; i < 576; i += 256) {
      f32x4 v = wb[i];
      s += fabsf(v.x) + fabsf(v.y) + fabsf(v.z) + fabsf(v.w);
    }
    #pragma unroll
    for (int off = 32; off > 0; off >>= 1) s += __shfl_down(s, off);
    __shared__ float red[4];
    if ((threadIdx.x & 63) == 0) red[threadIdx.x >> 6] = s;
    __syncthreads();
    if (threadIdx.x == 0) csum_part[id] = red[0] + red[1] + red[2] + red[3];
    return;
  }
  int b = bi / 58;
  int hp = bi - b * 58;
  unsigned short* dst = xp + ((size_t)b * 58 + hp) * 58 * 128;
  int gh = hp - 1;
  if ((unsigned)gh >= 56u) {  // full pad row
    uint4 ones = make_uint4(0x3F803F80u, 0x3F803F80u, 0x3F803F80u, 0x3F803F80u);
    for (int i = threadIdx.x; i < 928; i += 256) ((uint4*)dst)[i] = ones;
    return;
  }
  __shared__ unsigned short tile[128][61];
  const float* src = x + ((size_t)b * 128 * 56 + gh) * 56;
  for (int i = threadIdx.x; i < 128 * 14; i += 256) {
    int c = i / 14;
    int k = i - c * 14;
    f32x4 v = *(const f32x4*)(src + (size_t)c * 3136 + k * 4);
    tile[c][1 + 4 * k + 0] = f2bf(v.x);
    tile[c][1 + 4 * k + 1] = f2bf(v.y);
    tile[c][1 + 4 * k + 2] = f2bf(v.z);
    tile[c][1 + 4 * k + 3] = f2bf(v.w);
  }
  if (threadIdx.x < 128) {
    tile[threadIdx.x][0] = 0x3F80;
    tile[threadIdx.x][57] = 0x3F80;
  }
  __syncthreads();
  for (int i = threadIdx.x; i < 928; i += 256) {
    int wp = i >> 4;
    int c8 = i & 15;
    union { uint4 q; unsigned short h[8]; } u;
    #pragma unroll
    for (int j = 0; j < 8; ++j) u.h[j] = tile[c8 * 8 + j][wp];
    *(uint4*)(dst + (size_t)wp * 128 + c8 * 8) = u.q;
  }
}

// ---- kernel 2: W_eff -> bf16, swizzled layout for direct global_load_lds:
// stage s = t*2 + (i>>6) holds 128o x 64ch; element (o,i,t) ->
// wq[s*8192 + o*64 + ((c8 ^ (o&7)))*8 + (i&7)], c8 = (i>>3)&7. ----
__global__ __launch_bounds__(256) void binweight_kernel(
    const float* __restrict__ w, const float* __restrict__ csum_part,
    const float* __restrict__ scales, unsigned short* __restrict__ wq) {
  __shared__ float parts[320];
  __shared__ float coef[N_BASES];
  for (int i = threadIdx.x; i < 320; i += 256) parts[i] = csum_part[i];
  __syncthreads();
  if (threadIdx.x < N_BASES) {
    float s = 0.f;
    #pragma unroll 8
    for (int k = 0; k < 64; ++k) s += parts[threadIdx.x * 64 + k];
    coef[threadIdx.x] = scales[threadIdx.x] * s * (1.0f / (float)WELEM);
  }
  __syncthreads();
  int f = blockIdx.x * 256 + threadIdx.x;  // f = o*1152 + i*9 + t
  float s = 0.f;
  #pragma unroll
  for (int n = 0; n < N_BASES; ++n) {
    float cn = coef[n];
    float v = w[n * WELEM + f];
    s += (v > 0.f) ? cn : ((v < 0.f) ? -cn : 0.f);
  }
  int o = f / 1152;
  int rem = f - o * 1152;
  int i = rem / 9;
  int t = rem - i * 9;
  int half = i >> 6;
  int c8 = (i >> 3) & 7;
  int e = i & 7;
  wq[(size_t)(t * 2 + half) * 8192 + o * 64 + ((c8 ^ (o & 7)) << 3) + e] = f2bf(s);
}

// ---- kernel 3: implicit-GEMM conv, software-pipelined B staging.
// Block: 1 img x (8h x 16w) spatial x 128 cout. 256 thr = 4 waves;
// wave (mh = w>>1 spatial half, nh = w&1 cout half) computes M=64 x N=64.
// A: patch in LDS (XOR-swizzled, staged once, 46.1 KB).
// B: 16 KB half-tap tiles, DOUBLE-BUFFERED, staged via global_load_lds from
// pre-swizzled wq. T3-minimal 2-phase schedule: issue STAGE(s+1) -> compute
// stage s -> vmcnt(0)+s_barrier (raw, asm; no compiler-forced early drain).
// Hazards: compute-s reads btile[s&1], guaranteed by end-of-(s-1)
// vmcnt(0)+barrier (s=0: by the patch __syncthreads, stage-0 issued before
// patch staging). STAGE(s+1) writes btile[(s+1)&1], last read in compute
// s-1 which completed before the end-of-(s-1) barrier. LDS total 77 KB ->
// 2 blocks/CU. ----
__global__ __launch_bounds__(256, 2) void conv_kernel(
    const unsigned short* __restrict__ xp, const unsigned short* __restrict__ wq,
    float* __restrict__ out) {
  __shared__ unsigned short patch[23040];    // 180 sp x 128 ch (46.1 KB)
  __shared__ unsigned short btile[2][8192];  // 2 x (128 o x 64 ch) (2x16 KB)

  const int tid = threadIdx.x;
  const int blk = blockIdx.x;
  const int b = blk & 31;        // image
  const int tile = blk >> 5;     // 0..27 = hi*4 + wi
  const int hi = tile >> 2;      // 0..6
  const int wi = tile & 3;
  const int h0 = hi * 8;
  const int w0 = (wi == 3) ? 40 : wi * 16;

  const int lane = tid & 63;
  const int wave = tid >> 6;

  // ---- prologue: issue stage 0 glds now; latency hides under patch staging,
  // completion guaranteed by the __syncthreads() vmcnt(0) drain. ----
  {
    const unsigned short* g = wq + wave * 2048 + lane * 8;
    unsigned short* l = &btile[0][wave * 2048];
    #pragma unroll
    for (int j = 0; j < 4; ++j) glds16(g + j * 512, l + j * 512);
  }

  // ---- stage patch: 180 sp (10 rows x 18 px) x 16 chunks, swizzled ----
  const size_t rowstride = 58 * 128;
  for (int i = tid; i < 2880; i += 256) {
    int sp = i >> 4;
    int c16 = i & 15;
    int ph = sp / 18;           // 0..9
    int pw = sp - ph * 18;      // 0..17
    const unsigned short* gp = xp + ((size_t)b * 58 + (h0 + ph)) * rowstride +
                               (size_t)(w0 + pw) * 128 + c16 * 8;
    uint4 v = *(const uint4*)gp;
    *(uint4*)&patch[sp * 128 + ((c16 ^ (sp & 7)) << 3)] = v;
  }
  __syncthreads();  // patch ready; also drains stage-0 glds

  const int mh = wave >> 1;
  const int nh = wave & 1;
  const int l15 = lane & 15;
  const int quad = lane >> 4;

  f32x4 acc[4][4];
  #pragma unroll
  for (int mf = 0; mf < 4; ++mf)
    #pragma unroll
    for (int nf = 0; nf < 4; ++nf) acc[mf][nf] = (f32x4)0.f;

  #pragma unroll
  for (int t = 0; t < 9; ++t) {
    const int kh = t / 3;
    const int kw = t - kh * 3;
    int sp_mf[4];
    #pragma unroll
    for (int mf = 0; mf < 4; ++mf)
      sp_mf[mf] = (mh * 4 + mf + kh) * 18 + (l15 + kw);
    #pragma unroll
    for (int half = 0; half < 2; ++half) {
      const int s = t * 2 + half;
      // ---- prefetch stage s+1 into the other buffer (in flight across compute) ----
      if (s < 17) {
        const unsigned short* g =
            wq + (size_t)(s + 1) * 8192 + wave * 2048 + lane * 8;
        unsigned short* l = &btile[(s + 1) & 1][wave * 2048];
        #pragma unroll
        for (int j = 0; j < 4; ++j) glds16(g + j * 512, l + j * 512);
      }
      // ---- compute stage s from btile[s&1] ----
      const unsigned short* bt = btile[s & 1];
      #pragma unroll
      for (int kk = 0; kk < 2; ++kk) {
        const int kb = half * 2 + kk;
        bf16x8 af[4], bfr[4];
        #pragma unroll
        for (int mf = 0; mf < 4; ++mf) {
          int sp = sp_mf[mf];
          af[mf] = *(const bf16x8*)&patch[sp * 128 +
                                          (((kb * 4 + quad) ^ (sp & 7)) << 3)];
        }
        #pragma unroll
        for (int nf = 0; nf < 4; ++nf) {
          int o = nh * 64 + nf * 16 + l15;
          bfr[nf] = *(const bf16x8*)&bt[o * 64 +
                                        (((kk * 4 + quad) ^ (o & 7)) << 3)];
        }
        #pragma unroll
        for (int mf = 0; mf < 4; ++mf)
          #pragma unroll
          for (int nf = 0; nf < 4; ++nf)
            acc[mf][nf] = __builtin_amdgcn_mfma_f32_16x16x32_bf16(
                af[mf], bfr[nf], acc[mf][nf], 0, 0, 0);
      }
      // ---- counted drain AFTER compute: stage s+1 loads had the whole
      // compute phase to fly. Raw barrier (asm) => no forced early vmcnt(0). ----
      if (s < 17) {
        asm volatile("s_waitcnt vmcnt(0)" ::: "memory");
        asm volatile("s_barrier" ::: "memory");
      }
    }
  }

  // ---- epilogue: D row = quad*4+r = w-offset, col = l15 = cout-low.
  // lane's f32x4 = w0+quad*4 .. +3 at h = h0+mh*4+mf: full 64-B sectors. ----
  #pragma unroll
  for (int mf = 0; mf < 4; ++mf) {
    int h = h0 + mh * 4 + mf;
    #pragma unroll
    for (int nf = 0; nf < 4; ++nf) {
      int o = nh * 64 + nf * 16 + l15;
      float* p = out + (((size_t)b * 128 + o) * 56 + h) * 56 + w0 + quad * 4;
      *(f32x4*)p = acc[mf][nf];
    }
  }
}

extern "C" void kernel_launch(void* const* d_in, const int* in_sizes, int n_in,
                              void* d_out, int out_size, void* d_ws, size_t ws_size,
                              hipStream_t stream) {
  const float* x = (const float*)d_in[0];       // [32,128,56,56]
  const float* w = (const float*)d_in[1];       // [5,128,128,3,3]
  const float* scales = (const float*)d_in[2];  // [5]
  float* out = (float*)d_out;                   // [32,128,56,56]

  float* csum_part = (float*)d_ws;                                    // 320 floats
  unsigned short* wq = (unsigned short*)((char*)d_ws + 4096);         // 18*8192 bf16
  unsigned short* xpad = (unsigned short*)((char*)d_ws + 512 * 1024); // 32*58*58*128 bf16

  prep_fused<<<1856 + 320, 256, 0, stream>>>(x, w, xpad, csum_part);
  binweight_kernel<<<576, 256, 0, stream>>>(w, csum_part, scales, wq);
  conv_kernel<<<56 * 16, 256, 0, stream>>>(xpad, wq, out);
}